// Round 1
// baseline (593.154 us; speedup 1.0000x reference)
//
#include <hip/hip_runtime.h>
#include <cstdint>
#include <cstddef>

#define NEGV (-1e10f)

typedef short short8 __attribute__((ext_vector_type(8)));
typedef float f32x4 __attribute__((ext_vector_type(4)));

__device__ __forceinline__ float bf2f(short s) {
    union { float f; uint32_t u; } x;
    x.u = ((uint32_t)(uint16_t)s) << 16;
    return x.f;
}
__device__ __forceinline__ short f2bf(float f) {
    union { float f; uint32_t u; } x;
    x.f = f;
    uint32_t u = x.u;
    uint32_t r = (u + 0x7fffu + ((u >> 16) & 1u)) >> 16;
    return (short)r;
}

__device__ __forceinline__ void gl2lds16(const void* gsrc, void* ldst) {
    __builtin_amdgcn_global_load_lds(
        (const __attribute__((address_space(1))) void*)gsrc,
        (__attribute__((address_space(3))) void*)ldst, 16, 0, 0);
}

// ---------------------------------------------------------------------------
// Generic bf16 GEMM: C[M,N] = A[M,K] * BT[N,K]^T   (both operands row-major,
// K contiguous).  128x128 tile, BK=64, 4 waves of 64x64, mfma_f32_16x16x32_bf16.
// EPI: 0 = store f32 C, 1 = store bf16 C, 2 = fused score epilogue
// PAIR: A-tile is computed on the fly as g[i] ⊙ g[j] per pair row.
// ---------------------------------------------------------------------------
template <int EPI, bool PAIR>
__global__ __launch_bounds__(256) void gemm_bt(
    const short* __restrict__ A, int lda,
    const short* __restrict__ BT, int ldb,
    void* __restrict__ Cout, int ldc, int K,
    const short* __restrict__ G,          // g_bf [1024][512] (PAIR)
    const int* __restrict__ bjj,          // best_idx [51200] (PAIR)
    const int* __restrict__ fcode,        // feature code [51200] (EPI==2)
    const float* __restrict__ AB0,        // [1024][2048]: A0 | B0 (EPI==2)
    const float* __restrict__ Ftab,       // [18][1024] (EPI==2)
    const float* __restrict__ w2p,        // [1024] (EPI==2)
    float* __restrict__ sacc)             // [51200] (EPI==2)
{
    __shared__ short As[128 * 64];
    __shared__ short Bs[128 * 64];
    __shared__ int iL[128], jL[128], fcL[128];

    const int tid = threadIdx.x;
    const int lane = tid & 63;
    const int w = tid >> 6;
    const int quad = lane >> 4;
    const int l15 = lane & 15;
    const int bm = blockIdx.y, bn = blockIdx.x;

    if (PAIR) {
        if (tid < 128) {
            int p = bm * 128 + tid;
            iL[tid] = p / 50;
            jL[tid] = bjj[p];
            fcL[tid] = (EPI == 2) ? fcode[p] : 0;
        }
        __syncthreads();
    }

    f32x4 acc[4][4];
#pragma unroll
    for (int mi = 0; mi < 4; mi++)
#pragma unroll
        for (int ni = 0; ni < 4; ni++)
            acc[mi][ni] = {0.f, 0.f, 0.f, 0.f};

    const int mb = (w >> 1) * 64, nb = (w & 1) * 64;

    for (int k0 = 0; k0 < K; k0 += 64) {
        // ---- stage B tile (BT rows = output cols), async global->LDS, 16B/lane
#pragma unroll
        for (int c = 0; c < 4; c++) {
            int chunk = w * 4 + c;                 // 16 chunks of 8 rows
            int row = chunk * 8 + (lane >> 3);
            const short* src = BT + (size_t)(bn * 128 + row) * ldb + k0 + (lane & 7) * 8;
            gl2lds16(src, Bs + chunk * 512);
        }
        // ---- stage A tile
        if (!PAIR) {
#pragma unroll
            for (int c = 0; c < 4; c++) {
                int chunk = w * 4 + c;
                int row = chunk * 8 + (lane >> 3);
                const short* src = A + (size_t)(bm * 128 + row) * lda + k0 + (lane & 7) * 8;
                gl2lds16(src, As + chunk * 512);
            }
        } else {
#pragma unroll
            for (int it = 0; it < 4; it++) {
                int gidx = it * 256 + tid;         // 1024 granules of 8 bf16
                int r = gidx >> 3, g8 = gidx & 7;
                int i = iL[r], j = jL[r];
                short8 va = *(const short8*)(G + (size_t)i * 512 + k0 + g8 * 8);
                short8 vb = *(const short8*)(G + (size_t)j * 512 + k0 + g8 * 8);
                short8 vp;
#pragma unroll
                for (int e = 0; e < 8; e++)
                    vp[e] = f2bf(bf2f(va[e]) * bf2f(vb[e]));
                *(short8*)(As + r * 64 + g8 * 8) = vp;
            }
        }
        __syncthreads();
        // ---- MFMA over the 64-wide K slice
#pragma unroll
        for (int ks = 0; ks < 64; ks += 32) {
            short8 af[4], bfr[4];
#pragma unroll
            for (int mi = 0; mi < 4; mi++)
                af[mi] = *(const short8*)(As + (mb + mi * 16 + l15) * 64 + ks + quad * 8);
#pragma unroll
            for (int ni = 0; ni < 4; ni++)
                bfr[ni] = *(const short8*)(Bs + (nb + ni * 16 + l15) * 64 + ks + quad * 8);
#pragma unroll
            for (int mi = 0; mi < 4; mi++)
#pragma unroll
                for (int ni = 0; ni < 4; ni++)
                    acc[mi][ni] = __builtin_amdgcn_mfma_f32_16x16x32_bf16(
                        af[mi], bfr[ni], acc[mi][ni], 0, 0, 0);
        }
        __syncthreads();
    }

    if (EPI == 0 || EPI == 1) {
#pragma unroll
        for (int mi = 0; mi < 4; mi++)
#pragma unroll
            for (int ni = 0; ni < 4; ni++) {
                int col = bn * 128 + nb + ni * 16 + l15;
#pragma unroll
                for (int reg = 0; reg < 4; reg++) {
                    int rowg = bm * 128 + mb + mi * 16 + quad * 4 + reg;
                    if (EPI == 0)
                        ((float*)Cout)[(size_t)rowg * ldc + col] = acc[mi][ni][reg];
                    else
                        ((short*)Cout)[(size_t)rowg * ldc + col] = f2bf(acc[mi][ni][reg]);
                }
            }
    } else {
        // fused layer-2: s[p] += sum_h relu(acc + A0[i,h] + B0[j,h] + F[fc,h]) * w2[h]
#pragma unroll
        for (int mi = 0; mi < 4; mi++)
#pragma unroll
            for (int reg = 0; reg < 4; reg++) {
                int rloc = mb + mi * 16 + quad * 4 + reg;
                int p = bm * 128 + rloc;
                int i = iL[rloc], j = jL[rloc], fc = fcL[rloc];
                float rs = 0.f;
#pragma unroll
                for (int ni = 0; ni < 4; ni++) {
                    int h = bn * 128 + nb + ni * 16 + l15;
                    float pre = acc[mi][ni][reg] + AB0[(size_t)i * 2048 + h] +
                                AB0[(size_t)j * 2048 + 1024 + h] + Ftab[fc * 1024 + h];
                    rs += fmaxf(pre, 0.f) * w2p[h];
                }
#pragma unroll
                for (int m = 1; m < 16; m <<= 1) rs += __shfl_xor(rs, m);
                if (l15 == 0) atomicAdd(sacc + p, rs);
            }
    }
}

// ---------------------------------------------------------------------------
// Weight prep: transposed bf16 copies of W1 slices / Wf / coarse_W + pads
// ---------------------------------------------------------------------------
__global__ void prep_w_kernel(const float* __restrict__ W1, const float* __restrict__ Wf,
                              const float* __restrict__ cW, const float* __restrict__ W2,
                              const float* __restrict__ b1,
                              short* W1abT, short* W1cT, short* WfT, short* cwbf,
                              float* w2p, float* b1p) {
    int idx = blockIdx.x * 256 + threadIdx.x;
    const int S1 = 2048 * 512, S2 = 1024 * 512, S3 = 512 * 1024, S4 = 512 * 512;
    if (idx < S1) {  // W1abT[row= m*1024+hh][k] = W1[m*512+k][hh], zero-pad hh>=1000
        int row = idx >> 9, k = idx & 511;
        int m = row >> 10, hh = row & 1023;
        float v = (hh < 1000) ? W1[(size_t)(m * 512 + k) * 1000 + hh] : 0.f;
        W1abT[idx] = f2bf(v);
        return;
    }
    idx -= S1;
    if (idx < S2) {  // W1cT[hh][k] = W1[1024+k][hh]
        int hh = idx >> 9, k = idx & 511;
        float v = (hh < 1000) ? W1[(size_t)(1024 + k) * 1000 + hh] : 0.f;
        W1cT[idx] = f2bf(v);
        return;
    }
    idx -= S2;
    if (idx < S3) {  // WfT[n][k] = Wf[k][n]
        int n = idx >> 10, k = idx & 1023;
        WfT[idx] = f2bf(Wf[k * 512 + n]);
        return;
    }
    idx -= S3;
    if (idx < S4) { cwbf[idx] = f2bf(cW[idx]); return; }
    idx -= S4;
    if (idx < 1024) { w2p[idx] = (idx < 1000) ? W2[idx] : 0.f; return; }
    idx -= 1024;
    if (idx < 1024) { b1p[idx] = (idx < 1000) ? b1[idx] : 0.f; }
}

// phi tables projected through W1: Cg[8][1024], F[18][1024] (= dist + spk)
__global__ void prep_tab_kernel(const float* __restrict__ W1, const float* __restrict__ genre_e,
                                const float* __restrict__ dist_e, const float* __restrict__ spk_e,
                                float* Cg, float* Ftab) {
    int idx = blockIdx.x * 256 + threadIdx.x;
    if (idx < 8 * 1024) {
        int g = idx >> 10, h = idx & 1023;
        float v = 0.f;
        if (h < 1000)
            for (int e = 0; e < 20; e++) v += genre_e[g * 20 + e] * W1[(size_t)(1556 + e) * 1000 + h];
        Cg[idx] = v;
        return;
    }
    idx -= 8 * 1024;
    if (idx < 18 * 1024) {
        int code = idx >> 10, h = idx & 1023;
        int b = code >> 1, s2 = code & 1;  // s2=0 -> spk row 1 (same), 1 -> row 2
        float v = 0.f;
        if (h < 1000) {
            for (int e = 0; e < 20; e++) v += dist_e[b * 20 + e] * W1[(size_t)(1536 + e) * 1000 + h];
            for (int e = 0; e < 20; e++) v += spk_e[(s2 + 1) * 20 + e] * W1[(size_t)(1576 + e) * 1000 + h];
        }
        Ftab[idx] = v;
    }
}

__global__ void cvt_g_kernel(const float* __restrict__ g, short* g_bf) {
    int idx = blockIdx.x * 256 + threadIdx.x;
    if (idx < 1024 * 512) g_bf[idx] = f2bf(g[idx]);
}

// Exact top-50 per row: 1 wave per row, 16 candidates per lane in registers.
__global__ __launch_bounds__(64) void topk_kernel(
    const float* __restrict__ ant, const float* __restrict__ ms,
    const int* __restrict__ sidx, const int* __restrict__ eidx,
    const int* __restrict__ spk,
    float* __restrict__ bscore, int* __restrict__ bjj, int* __restrict__ fcodes) {
    int i = blockIdx.x;
    int lane = threadIdx.x;
    float v[16];
    float si = ms[i];
#pragma unroll
    for (int c = 0; c < 16; c++) {
        int j = lane * 16 + c;
        float val = ant[(size_t)i * 1024 + j] + si + ms[j];
        v[c] = (j < i) ? val : (val + NEGV);  // f32 add: rounds to exactly -1e10
    }
    int ei = eidx[i];
    int spi = spk[i];
    for (int r = 0; r < 50; r++) {
        float bv = -3.4e38f;
        int bj = 1 << 30;
#pragma unroll
        for (int c = 0; c < 16; c++)
            if (v[c] > bv) { bv = v[c]; bj = lane * 16 + c; }
#pragma unroll
        for (int m = 1; m < 64; m <<= 1) {
            float ov = __shfl_xor(bv, m);
            int oj = __shfl_xor(bj, m);
            if (ov > bv || (ov == bv && oj < bj)) { bv = ov; bj = oj; }
        }
        if (lane == 0) {
            bscore[i * 50 + r] = bv;
            bjj[i * 50 + r] = bj;
            int d = ei - sidx[bj];
            int bin = (d > 1) + (d > 2) + (d > 3) + (d > 4) + (d > 8) + (d > 16) + (d > 32) + (d > 64);
            int lab = (spi == spk[bj]) ? 0 : 1;
            fcodes[i * 50 + r] = bin * 2 + lab;
        }
#pragma unroll
        for (int c = 0; c < 16; c++)
            if (bj == lane * 16 + c) v[c] = -3.4e38f;
    }
}

__global__ void fixA_kernel(float* AB0, const float* __restrict__ Cg,
                            const float* __restrict__ b1p, const int* __restrict__ genre) {
    int idx = blockIdx.x * 256 + threadIdx.x;
    if (idx >= 1024 * 1024) return;
    int i = idx >> 10, h = idx & 1023;
    AB0[(size_t)i * 2048 + h] += Cg[genre[i] * 1024 + h] + b1p[h];
}

__global__ void init_sacc_kernel(float* sacc, const float* __restrict__ b2) {
    int idx = blockIdx.x * 256 + threadIdx.x;
    if (idx < 51200) sacc[idx] = b2[0];
}

// softmax over {eps, antecedents} + expected antecedent a_n; also builds [g|a_n] bf16
__global__ __launch_bounds__(256) void softmax_an_kernel(
    const float* __restrict__ sacc, const float* __restrict__ bscore,
    const int* __restrict__ bjj, const short* __restrict__ g_bf,
    float* __restrict__ a_n, short* __restrict__ cat_bf) {
    int i = blockIdx.x;
    int tid = threadIdx.x;
    __shared__ float pw[51];
    __shared__ int cidx[51];
    if (tid < 51) {
        if (tid == 0) { pw[0] = 0.f; cidx[0] = i; }
        else {
            int kk = tid - 1;
            int vc = (i < 50) ? i : 50;
            pw[tid] = (kk < vc) ? (sacc[i * 50 + kk] + bscore[i * 50 + kk]) : NEGV;
            cidx[tid] = bjj[i * 50 + kk];
        }
    }
    __syncthreads();
    if (tid == 0) {
        float m = pw[0];
        for (int c = 1; c < 51; c++) m = fmaxf(m, pw[c]);
        float s = 0.f;
        for (int c = 0; c < 51; c++) { float e = __expf(pw[c] - m); pw[c] = e; s += e; }
        float inv = 1.f / s;
        for (int c = 0; c < 51; c++) pw[c] *= inv;
    }
    __syncthreads();
    for (int d = tid; d < 512; d += 256) {
        float a = 0.f;
        for (int c = 0; c < 51; c++) a += pw[c] * bf2f(g_bf[(size_t)cidx[c] * 512 + d]);
        a_n[i * 512 + d] = a;
        cat_bf[i * 1024 + d] = g_bf[i * 512 + d];
        cat_bf[i * 1024 + 512 + d] = f2bf(a);
    }
}

__global__ void update_kernel(const float* __restrict__ f_pre, const float* __restrict__ bfv,
                              const float* __restrict__ a_n, short* g_bf) {
    int idx = blockIdx.x * 256 + threadIdx.x;
    if (idx >= 1024 * 512) return;
    int i = idx >> 9, d = idx & 511;
    if (i == 0) return;  // span 0 is never refined
    float x = f_pre[idx] + bfv[d];
    float f = 1.f / (1.f + __expf(-x));
    float oldv = bf2f(g_bf[idx]);
    g_bf[idx] = f2bf(f * oldv + (1.f - f) * a_n[idx]);
}

__global__ void finalize_kernel(const float* __restrict__ sacc, const float* __restrict__ bscore,
                                float* __restrict__ out) {
    int idx = blockIdx.x * 256 + threadIdx.x;
    if (idx >= 1024 * 51) return;
    int i = idx / 51, c = idx % 51;
    float v;
    if (i == 0) v = (c <= 1) ? 0.f : NEGV;
    else if (c == 0) v = 0.f;
    else {
        int kk = c - 1;
        int vc = (i < 50) ? i : 50;
        v = (kk < vc) ? (sacc[i * 50 + kk] + bscore[i * 50 + kk]) : NEGV;
    }
    out[idx] = v;
}

// ---------------------------------------------------------------------------
// Workspace layout (all sizes multiples of 256 B; total ~25.4 MB)
// ---------------------------------------------------------------------------
static constexpr size_t OFF_W1ABT = 0;          // 2048*512*2  = 2097152
static constexpr size_t OFF_W1CT  = 2097152;    // 1024*512*2  = 1048576
static constexpr size_t OFF_WFT   = 3145728;    // 512*1024*2  = 1048576
static constexpr size_t OFF_CWBF  = 4194304;    // 512*512*2   = 524288
static constexpr size_t OFF_W2P   = 4718592;    // 1024*4      = 4096
static constexpr size_t OFF_B1P   = 4722688;    // 1024*4      = 4096
static constexpr size_t OFF_CG    = 4726784;    // 8*1024*4    = 32768
static constexpr size_t OFF_FTAB  = 4759552;    // 18*1024*4   = 73728
static constexpr size_t OFF_GBF   = 4833280;    // 1024*512*2  = 1048576
static constexpr size_t OFF_TMPBF = 5881856;    // 1024*512*2  = 1048576
static constexpr size_t OFF_ANT   = 6930432;    // 1024*1024*4 = 4194304
static constexpr size_t OFF_BSC   = 11124736;   // 51200*4     = 204800
static constexpr size_t OFF_BJ    = 11329536;   // 51200*4     = 204800
static constexpr size_t OFF_FC    = 11534336;   // 51200*4     = 204800
static constexpr size_t OFF_AB0   = 11739136;   // 1024*2048*4 = 8388608
static constexpr size_t OFF_SACC  = 20127744;   // 51200*4     = 204800
static constexpr size_t OFF_AN    = 20332544;   // 1024*512*4  = 2097152
static constexpr size_t OFF_CATBF = 22429696;   // 1024*1024*2 = 2097152
static constexpr size_t OFF_FPRE  = 24526848;   // 1024*512*4  = 2097152

extern "C" void kernel_launch(void* const* d_in, const int* in_sizes, int n_in,
                              void* d_out, int out_size, void* d_ws, size_t ws_size,
                              hipStream_t stream) {
    const float* g_i   = (const float*)d_in[0];
    const float* ms    = (const float*)d_in[1];
    const float* diste = (const float*)d_in[2];
    const float* gene  = (const float*)d_in[3];
    const float* spke  = (const float*)d_in[4];
    const float* cW    = (const float*)d_in[5];
    const float* W1    = (const float*)d_in[6];
    const float* b1    = (const float*)d_in[7];
    const float* W2    = (const float*)d_in[8];
    const float* b2    = (const float*)d_in[9];
    const float* Wf    = (const float*)d_in[10];
    const float* bfv   = (const float*)d_in[11];
    const int* sidx    = (const int*)d_in[12];
    const int* eidx    = (const int*)d_in[13];
    const int* gid     = (const int*)d_in[14];
    const int* spk     = (const int*)d_in[15];
    float* out = (float*)d_out;

    char* ws = (char*)d_ws;
    short* W1abT = (short*)(ws + OFF_W1ABT);
    short* W1cT  = (short*)(ws + OFF_W1CT);
    short* WfT   = (short*)(ws + OFF_WFT);
    short* cwbf  = (short*)(ws + OFF_CWBF);
    float* w2p   = (float*)(ws + OFF_W2P);
    float* b1p   = (float*)(ws + OFF_B1P);
    float* Cg    = (float*)(ws + OFF_CG);
    float* Ftab  = (float*)(ws + OFF_FTAB);
    short* g_bf  = (short*)(ws + OFF_GBF);
    short* tmpbf = (short*)(ws + OFF_TMPBF);
    float* ant   = (float*)(ws + OFF_ANT);
    float* bsc   = (float*)(ws + OFF_BSC);
    int*   bjj   = (int*)(ws + OFF_BJ);
    int*   fcode = (int*)(ws + OFF_FC);
    float* AB0   = (float*)(ws + OFF_AB0);
    float* sacc  = (float*)(ws + OFF_SACC);
    float* a_n   = (float*)(ws + OFF_AN);
    short* catbf = (short*)(ws + OFF_CATBF);
    float* f_pre = (float*)(ws + OFF_FPRE);

    // --- prep ---
    prep_w_kernel<<<9224, 256, 0, stream>>>(W1, Wf, cW, W2, b1, W1abT, W1cT, WfT, cwbf, w2p, b1p);
    prep_tab_kernel<<<104, 256, 0, stream>>>(W1, gene, diste, spke, Cg, Ftab);
    cvt_g_kernel<<<2048, 256, 0, stream>>>(g_i, g_bf);

    // --- coarse scores: tmp = g @ cW^T (bf16 out), ant = tmp @ g^T ---
    gemm_bt<1, false><<<dim3(4, 8), 256, 0, stream>>>(
        g_bf, 512, cwbf, 512, tmpbf, 512, 512,
        nullptr, nullptr, nullptr, nullptr, nullptr, nullptr, nullptr);
    gemm_bt<0, false><<<dim3(8, 8), 256, 0, stream>>>(
        tmpbf, 512, g_bf, 512, ant, 1024, 512,
        nullptr, nullptr, nullptr, nullptr, nullptr, nullptr, nullptr);

    // --- exact top-50 + pair feature codes ---
    topk_kernel<<<1024, 64, 0, stream>>>(ant, ms, sidx, eidx, spk, bsc, bjj, fcode);

    // --- two higher-order iterations ---
    for (int t = 0; t < 2; t++) {
        // AB0 = g @ [W1a | W1b]  (1024 x 2048)
        gemm_bt<0, false><<<dim3(16, 8), 256, 0, stream>>>(
            g_bf, 512, W1abT, 512, AB0, 2048, 512,
            nullptr, nullptr, nullptr, nullptr, nullptr, nullptr, nullptr);
        fixA_kernel<<<4096, 256, 0, stream>>>(AB0, Cg, b1p, gid);
        init_sacc_kernel<<<200, 256, 0, stream>>>(sacc, b2);
        // fused (g_i ⊙ g_j) @ W1c  + relu·w2 reduction -> sacc
        gemm_bt<2, true><<<dim3(8, 400), 256, 0, stream>>>(
            nullptr, 0, W1cT, 512, nullptr, 0, 512,
            g_bf, bjj, fcode, AB0, Ftab, w2p, sacc);
        if (t == 0) {
            softmax_an_kernel<<<1024, 256, 0, stream>>>(sacc, bsc, bjj, g_bf, a_n, catbf);
            gemm_bt<0, false><<<dim3(4, 8), 256, 0, stream>>>(
                catbf, 1024, WfT, 1024, f_pre, 512, 1024,
                nullptr, nullptr, nullptr, nullptr, nullptr, nullptr, nullptr);
            update_kernel<<<2048, 256, 0, stream>>>(f_pre, bfv, a_n, g_bf);
        } else {
            finalize_kernel<<<204, 256, 0, stream>>>(sacc, bsc, out);
        }
    }
}